// Round 1
// 264.914 us; speedup vs baseline: 1.1152x; 1.1152x over previous
//
#include <hip/hip_runtime.h>

// GCNConvSC: out = x + (D^-1/2 (A+I) D^-1/2) x W + b
// R7: R6 spine (295us, k_gather=73us) + latency attack on k_gather.
//   - k_gather was 16 VGPRs: ONE row load in flight per quarter-wave ->
//     latency-bound (VALU 40%, HBM 38%, neither saturated). Unroll-2 doubles
//     outstanding 256B gathers per wave.
//   - rows pre-scaled by dis in k_cvt (xh' = bf16(dis[r]*x[r])): removes the
//     per-edge dependent dis[s] load (VMEM issues/iter 6->4). Self-loop becomes
//     weight-1 (xh'_d = dd*xh_d), final scale by dd unchanged.
//   - pipeline reordered: CSR build first, then k_cvt (needs dis), gather, gemm.
// FETCH floor note: gather FETCH ~194MB ~= 8 XCDs x 25.6MB table (random src,
// every XCD reads whole table) -- already at floor; the win must come from ILP.
// LESSON (R5): fp32 atomicAdd on __shared__ takes the slow per-lane path; no
// fp32 atomics anywhere.
//
// Pipeline:
//  1. k_hist   per-16384-edge-chunk histogram over NB=782 buckets (dst>>7)
//  2. k_part/k_mid/k_applyg  exclusive scan of hist[k][blk] -> base; ptr[N]=E
//  3. k_scat   packed[pos] = src | (dst&127)<<17, bucket-grouped (int LDS fill)
//  4. k_sort   block/bucket: count+scan in LDS -> ptr, dis, dst-sorted csr_src
//  5. k_cvt    xh'[r]=bf16(dis[r]*x[r]) into out rows' second 256B halves
//  6. k_gather wave/node, quarter-wave/edge, unroll-2: agg[d]=dd*(sum xh'_s + xh'_d)
//  7. k_gemm   out = x + agg @ W + b   (bf16 MFMA 16x16x32, W^T in LDS)

typedef __attribute__((ext_vector_type(8))) short short8;
typedef __attribute__((ext_vector_type(4))) float floatx4;

__device__ inline unsigned bf16rne(float f) {
    unsigned u = __builtin_bit_cast(unsigned, f);
    return (u + 0x7FFFu + ((u >> 16) & 1u)) >> 16;
}
__device__ inline unsigned pack2(float lo, float hi) {
    return bf16rne(lo) | (bf16rne(hi) << 16);
}
__device__ inline float bflo(unsigned u) { return __builtin_bit_cast(float, u << 16); }
__device__ inline float bfhi(unsigned u) { return __builtin_bit_cast(float, u & 0xFFFF0000u); }

#define CHUNK 16384   // edges per hist/scat block
#define NPB   128     // nodes per bucket (dst>>7)
#define MAXNB 1024    // LDS bound for hist/fill arrays (NB=782)
#define SRCB  17      // src bits in packed word (N=100000 < 2^17)
#define SRCMASK ((1u << SRCB) - 1u)

__global__ void k_cvt(const float* __restrict__ x, const float* __restrict__ dis,
                      char* __restrict__ outc, int N) {
    int t = blockIdx.x * blockDim.x + threadIdx.x;
    if (t >= N * 16) return;
    int r = t >> 4, g = t & 15;
    float d = dis[r];
    const float* p = x + (size_t)r * 128 + g * 8;
    float4 a = *(const float4*)p;
    float4 c = *(const float4*)(p + 4);
    uint4 v;
    v.x = pack2(d * a.x, d * a.y); v.y = pack2(d * a.z, d * a.w);
    v.z = pack2(d * c.x, d * c.y); v.w = pack2(d * c.z, d * c.w);
    *(uint4*)(outc + (size_t)r * 512 + 256 + g * 16) = v;
}

__global__ __launch_bounds__(256) void k_hist(const int* __restrict__ dst,
                                              int* __restrict__ hist,
                                              int E, int NB, int NBLK) {
    __shared__ int h[MAXNB];
    int tid = threadIdx.x, b = blockIdx.x;
    for (int i = tid; i < NB; i += 256) h[i] = 0;
    __syncthreads();
    int e0 = b * CHUNK, e1 = min(e0 + CHUNK, E);
    for (int e = e0 + tid; e < e1; e += 256) atomicAdd(&h[dst[e] >> 7], 1);
    __syncthreads();
    for (int k = tid; k < NB; k += 256) hist[(size_t)k * NBLK + b] = h[k];
}

// 3-kernel exclusive scan over M ints (M <= 128*1024)
__global__ __launch_bounds__(256) void k_part(const int* __restrict__ a,
                                              int* __restrict__ part, int M) {
    __shared__ int sums[256];
    int tid = threadIdx.x;
    int base = blockIdx.x * 1024 + tid * 4;
    int s = 0;
#pragma unroll
    for (int k = 0; k < 4; ++k) { int i = base + k; if (i < M) s += a[i]; }
    sums[tid] = s;
    __syncthreads();
    for (int off = 128; off > 0; off >>= 1) {
        if (tid < off) sums[tid] += sums[tid + off];
        __syncthreads();
    }
    if (tid == 0) part[blockIdx.x] = sums[0];
}

__global__ __launch_bounds__(128) void k_mid(int* __restrict__ part,
                                             int* __restrict__ ptrN,
                                             int nblk, int E) {
    __shared__ int s[128];
    int tid = threadIdx.x;
    s[tid] = (tid < nblk) ? part[tid] : 0;
    __syncthreads();
    for (int off = 1; off < 128; off <<= 1) {
        int v = (tid >= off) ? s[tid - off] : 0;
        __syncthreads();
        s[tid] += v;
        __syncthreads();
    }
    if (tid < nblk) part[tid] = tid ? s[tid - 1] : 0;
    if (tid == 0) ptrN[0] = E;
}

__global__ __launch_bounds__(256) void k_applyg(const int* __restrict__ a,
                                                const int* __restrict__ part,
                                                int* __restrict__ out, int M) {
    __shared__ int sums[256];
    int tid = threadIdx.x;
    int base = blockIdx.x * 1024 + tid * 4;
    int c[4];
    int s = 0;
#pragma unroll
    for (int k = 0; k < 4; ++k) {
        int i = base + k;
        c[k] = (i < M) ? a[i] : 0;
        s += c[k];
    }
    sums[tid] = s;
    __syncthreads();
    for (int off = 1; off < 256; off <<= 1) {
        int v = (tid >= off) ? sums[tid - off] : 0;
        __syncthreads();
        sums[tid] += v;
        __syncthreads();
    }
    int run = part[blockIdx.x] + (tid ? sums[tid - 1] : 0);
#pragma unroll
    for (int k = 0; k < 4; ++k) {
        int i = base + k;
        if (i < M) { out[i] = run; run += c[k]; }
    }
}

__global__ __launch_bounds__(256) void k_scat(const int* __restrict__ ei,
                                              const int* __restrict__ base,
                                              unsigned* __restrict__ packed,
                                              int E, int NB, int NBLK) {
    __shared__ int fill[MAXNB];
    int tid = threadIdx.x, b = blockIdx.x;
    for (int k = tid; k < NB; k += 256) fill[k] = base[(size_t)k * NBLK + b];
    __syncthreads();
    int e0 = b * CHUNK, e1 = min(e0 + CHUNK, E);
    for (int e = e0 + tid; e < e1; e += 256) {
        int s = ei[e];
        int d = ei[E + e];
        int pos = atomicAdd(&fill[d >> 7], 1);
        packed[pos] = (unsigned)s | ((unsigned)(d & (NPB - 1)) << SRCB);
    }
}

// one block per bucket: counting-sort its segment by local dst.
// All global writes land in this block's own ~8KB segment (L2-combined).
__global__ __launch_bounds__(256) void k_sort(const unsigned* __restrict__ packed,
                                              const int* __restrict__ base,
                                              int* __restrict__ csr_src,
                                              int* __restrict__ ptr,
                                              float* __restrict__ dis,
                                              int E, int NB, int NBLK, int N) {
    __shared__ int cnt[NPB], scn[NPB], fill[NPB];
    int tid = threadIdx.x, k = blockIdx.x;
    int s0 = base[(size_t)k * NBLK];
    int s1 = (k + 1 < NB) ? base[(size_t)(k + 1) * NBLK] : E;
    if (tid < NPB) cnt[tid] = 0;
    __syncthreads();
    for (int j = s0 + tid; j < s1; j += 256) atomicAdd(&cnt[packed[j] >> SRCB], 1);
    __syncthreads();
    if (tid < NPB) scn[tid] = cnt[tid];
    __syncthreads();
    for (int off = 1; off < NPB; off <<= 1) {
        int v = (tid < NPB && tid >= off) ? scn[tid - off] : 0;
        __syncthreads();
        if (tid < NPB) scn[tid] += v;
        __syncthreads();
    }
    if (tid < NPB) {
        int excl = scn[tid] - cnt[tid];
        fill[tid] = excl;
        int gn = k * NPB + tid;
        if (gn < N) {
            ptr[gn] = s0 + excl;
            dis[gn] = rsqrtf((float)(cnt[tid] + 1));  // +1 self loop
        }
    }
    __syncthreads();
    for (int j = s0 + tid; j < s1; j += 256) {
        unsigned p = packed[j];
        int loc = atomicAdd(&fill[p >> SRCB], 1);
        csr_src[s0 + loc] = (int)(p & SRCMASK);
    }
}

// one wave per node; quarter-wave q (16 lanes x 16B = 256B bf16 row) handles
// edges j = lo+q, lo+q+4, ...  Unroll-2: 8 row-gathers in flight per wave.
// Rows are pre-scaled by dis[src], so per edge it's a pure add; self-loop is
// weight-1; final scale by dd = dis[node].
#define ACC8(v)                         \
    do {                                \
        acc[0] += bflo((v).x);          \
        acc[1] += bfhi((v).x);          \
        acc[2] += bflo((v).y);          \
        acc[3] += bfhi((v).y);          \
        acc[4] += bflo((v).z);          \
        acc[5] += bfhi((v).z);          \
        acc[6] += bflo((v).w);          \
        acc[7] += bfhi((v).w);          \
    } while (0)

__global__ __launch_bounds__(256) void k_gather(char* __restrict__ outc,
                                                const int* __restrict__ csr_src,
                                                const int* __restrict__ ptr,
                                                const float* __restrict__ dis,
                                                int N) {
    int lane = threadIdx.x & 63;
    int q = lane >> 4, sub = lane & 15;
    int node = (blockIdx.x * blockDim.x + threadIdx.x) >> 6;
    if (node >= N) return;
    int lo = ptr[node], hi = ptr[node + 1];
    float dd = dis[node];
    const char* xb = outc + 256 + (size_t)sub * 16;  // pre-scaled bf16 row halves

    float acc[8] = {0.f, 0.f, 0.f, 0.f, 0.f, 0.f, 0.f, 0.f};

    if (q == 0) {  // self-loop: pre-scaled row, weight 1
        uint4 v = *(const uint4*)(xb + (size_t)node * 512);
        ACC8(v);
    }
    int j = lo + q;
    for (; j + 4 < hi; j += 8) {
        int s0 = csr_src[j];
        int s1 = csr_src[j + 4];
        uint4 v0 = *(const uint4*)(xb + (size_t)s0 * 512);
        uint4 v1 = *(const uint4*)(xb + (size_t)s1 * 512);
        ACC8(v0);
        ACC8(v1);
    }
    if (j < hi) {
        int s = csr_src[j];
        uint4 v = *(const uint4*)(xb + (size_t)s * 512);
        ACC8(v);
    }
#pragma unroll
    for (int i = 0; i < 8; ++i) {
        acc[i] += __shfl_xor(acc[i], 16);
        acc[i] += __shfl_xor(acc[i], 32);
    }
    if (q == 0) {
        uint4 o;
        o.x = pack2(dd * acc[0], dd * acc[1]);
        o.y = pack2(dd * acc[2], dd * acc[3]);
        o.z = pack2(dd * acc[4], dd * acc[5]);
        o.w = pack2(dd * acc[6], dd * acc[7]);
        *(uint4*)(outc + (size_t)node * 512 + sub * 16) = o;
    }
}

// MFMA GEMM: block = 256 thr (4 waves), 128 rows/block (wave: 2 row-tiles of 16).
// A = agg_bf16 (out rows' first halves), B = W^T bf16 in LDS.
// C/D layout: col=lane&15, row=(lane>>4)*4+reg.
__global__ __launch_bounds__(256) void k_gemm(const float* __restrict__ x,
                                              const float* __restrict__ W,
                                              const float* __restrict__ bias,
                                              float* __restrict__ out, int N) {
    __shared__ short Wt[128 * 136];
    int tid = threadIdx.x;
    for (int i = tid; i < 8192; i += 256) {
        int n = i & 127, k2 = i >> 7;
        float w0 = W[(size_t)(2 * k2) * 128 + n];
        float w1 = W[(size_t)(2 * k2 + 1) * 128 + n];
        *(unsigned*)(Wt + (size_t)n * 136 + 2 * k2) = pack2(w0, w1);
    }
    __syncthreads();

    int lane = tid & 63, wv = tid >> 6;
    int quad = lane >> 4, l16 = lane & 15;
    size_t rowb = (size_t)blockIdx.x * 128 + wv * 32;
    const char* aggc = (const char*)out;

    floatx4 acc[2][8];
#pragma unroll
    for (int rt = 0; rt < 2; ++rt)
#pragma unroll
        for (int c = 0; c < 8; ++c) acc[rt][c] = (floatx4)0.0f;

    size_t r0 = rowb + l16;      if (r0 >= (size_t)N) r0 = N - 1;
    size_t r1 = rowb + 16 + l16; if (r1 >= (size_t)N) r1 = N - 1;

    for (int ks = 0; ks < 4; ++ks) {
        int koff = (quad * 8 + ks * 32) * 2;
        short8 a0 = *(const short8*)(aggc + r0 * 512 + koff);
        short8 a1 = *(const short8*)(aggc + r1 * 512 + koff);
#pragma unroll
        for (int c = 0; c < 8; ++c) {
            short8 bf = *(const short8*)(Wt + (size_t)(c * 16 + l16) * 136 + quad * 8 + ks * 32);
            acc[0][c] = __builtin_amdgcn_mfma_f32_16x16x32_bf16(a0, bf, acc[0][c], 0, 0, 0);
            acc[1][c] = __builtin_amdgcn_mfma_f32_16x16x32_bf16(a1, bf, acc[1][c], 0, 0, 0);
        }
    }

#pragma unroll
    for (int rt = 0; rt < 2; ++rt) {
#pragma unroll
        for (int c = 0; c < 8; ++c) {
            float bb = bias[c * 16 + l16];
#pragma unroll
            for (int r = 0; r < 4; ++r) {
                size_t row = rowb + rt * 16 + quad * 4 + r;
                if (row < (size_t)N) {
                    size_t idx = row * 128 + c * 16 + l16;
                    out[idx] = x[idx] + acc[rt][c][r] + bb;
                }
            }
        }
    }
}

extern "C" void kernel_launch(void* const* d_in, const int* in_sizes, int n_in,
                              void* d_out, int out_size, void* d_ws, size_t ws_size,
                              hipStream_t stream) {
    const float* x  = (const float*)d_in[0];
    const int*   ei = (const int*)d_in[1];   // [2, E]: src row then dst row
    const float* W  = (const float*)d_in[2];
    const float* b  = (const float*)d_in[3];
    float* out = (float*)d_out;

    int N = in_sizes[0] / 128;
    int E = in_sizes[1] / 2;
    int NB   = (N + NPB - 1) / NPB;          // 782 buckets
    int NBLK = (E + CHUNK - 1) / CHUNK;      // 98 chunks
    int M    = NB * NBLK;                    // 76636
    int nscan = (M + 1023) / 1024;           // 75 (<=128)

    // ws: packed[E] | csr_src[E] | dis[N] | ptr[N+1] | hist[M] | base[M] | part[128]
    char* w = (char*)d_ws;
    unsigned* packed = (unsigned*)w; w += (size_t)E * 4;
    int*   csr_src = (int*)w;   w += (size_t)E * 4;
    float* dis     = (float*)w; w += (size_t)N * 4;
    int*   ptr     = (int*)w;   w += (size_t)(N + 1) * 4;
    int*   hist    = (int*)w;   w += (size_t)M * 4;
    int*   base    = (int*)w;   w += (size_t)M * 4;
    int*   part    = (int*)w;

    k_hist<<<NBLK, 256, 0, stream>>>(ei + E, hist, E, NB, NBLK);
    k_part<<<nscan, 256, 0, stream>>>(hist, part, M);
    k_mid<<<1, 128, 0, stream>>>(part, ptr + N, nscan, E);
    k_applyg<<<nscan, 256, 0, stream>>>(hist, part, base, M);
    k_scat<<<NBLK, 256, 0, stream>>>(ei, base, packed, E, NB, NBLK);
    k_sort<<<NB, 256, 0, stream>>>(packed, base, csr_src, ptr, dis, E, NB, NBLK, N);
    k_cvt<<<(N * 16 + 255) / 256, 256, 0, stream>>>(x, dis, (char*)out, N);
    k_gather<<<((size_t)N * 64 + 255) / 256, 256, 0, stream>>>((char*)out, csr_src, ptr, dis, N);
    k_gemm<<<(N + 127) / 128, 256, 0, stream>>>(x, W, b, out, N);
}

// Round 2
// 246.147 us; speedup vs baseline: 1.2002x; 1.0762x over previous
//
#include <hip/hip_runtime.h>

// GCNConvSC: out = x + (D^-1/2 (A+I) D^-1/2) x W + b
// R8: R7 spine (265us, k_gather=61us) + deeper MLP in gather + CSR-build
// parallelism.
//   - k_gather unroll-2 -> unroll-4 (+mid-2 tail): R7 counters (VALU 46%,
//     HBM 45%, occ 70%, VGPR=20) show nothing saturated => still latency-bound
//     with only 2 rows in flight. 4 outstanding 256B gathers per wave.
//   - k_hist/k_scat ran with NBLK=98 blocks -> 158/256 CUs idle. CHUNK is now
//     a runtime arg, default 6144 (261 blocks); k_mid widened to 256 threads
//     (nscan<=256). Fallback to CHUNK=16384 if ws_size too small.
// FETCH floor note: gather FETCH ~190MB ~= 8 XCDs x 25.6MB table (random src,
// every XCD pulls whole table through its L2) -- at floor; wins must come from
// ILP until L3->L2 BW saturates. If gather plateaus ~55us+ with VALU<50%,
// it's L3-BW-bound -> attack bytes next.
// LESSON (R5): fp32 atomicAdd on __shared__ takes the slow per-lane path; no
// fp32 atomics anywhere. fp8 rows rejected: ~16x bf16 rounding error, absmax
// already at 0.03125.
//
// Pipeline:
//  1. k_hist   per-chunk histogram over NB=782 buckets (dst>>7)
//  2. k_part/k_mid/k_applyg  exclusive scan of hist[k][blk] -> base; ptr[N]=E
//  3. k_scat   packed[pos] = src | (dst&127)<<17, bucket-grouped (int LDS fill)
//  4. k_sort   block/bucket: count+scan in LDS -> ptr, dis, dst-sorted csr_src
//  5. k_cvt    xh'[r]=bf16(dis[r]*x[r]) into out rows' second 256B halves
//  6. k_gather wave/node, quarter-wave/edge, unroll-4: agg[d]=dd*(sum xh'_s + xh'_d)
//  7. k_gemm   out = x + agg @ W + b   (bf16 MFMA 16x16x32, W^T in LDS)

typedef __attribute__((ext_vector_type(8))) short short8;
typedef __attribute__((ext_vector_type(4))) float floatx4;

__device__ inline unsigned bf16rne(float f) {
    unsigned u = __builtin_bit_cast(unsigned, f);
    return (u + 0x7FFFu + ((u >> 16) & 1u)) >> 16;
}
__device__ inline unsigned pack2(float lo, float hi) {
    return bf16rne(lo) | (bf16rne(hi) << 16);
}
__device__ inline float bflo(unsigned u) { return __builtin_bit_cast(float, u << 16); }
__device__ inline float bfhi(unsigned u) { return __builtin_bit_cast(float, u & 0xFFFF0000u); }

#define NPB   128     // nodes per bucket (dst>>7)
#define MAXNB 1024    // LDS bound for hist/fill arrays (NB=782)
#define SRCB  17      // src bits in packed word (N=100000 < 2^17)
#define SRCMASK ((1u << SRCB) - 1u)

__global__ void k_cvt(const float* __restrict__ x, const float* __restrict__ dis,
                      char* __restrict__ outc, int N) {
    int t = blockIdx.x * blockDim.x + threadIdx.x;
    if (t >= N * 16) return;
    int r = t >> 4, g = t & 15;
    float d = dis[r];
    const float* p = x + (size_t)r * 128 + g * 8;
    float4 a = *(const float4*)p;
    float4 c = *(const float4*)(p + 4);
    uint4 v;
    v.x = pack2(d * a.x, d * a.y); v.y = pack2(d * a.z, d * a.w);
    v.z = pack2(d * c.x, d * c.y); v.w = pack2(d * c.z, d * c.w);
    *(uint4*)(outc + (size_t)r * 512 + 256 + g * 16) = v;
}

__global__ __launch_bounds__(256) void k_hist(const int* __restrict__ dst,
                                              int* __restrict__ hist,
                                              int E, int NB, int NBLK, int chunk) {
    __shared__ int h[MAXNB];
    int tid = threadIdx.x, b = blockIdx.x;
    for (int i = tid; i < NB; i += 256) h[i] = 0;
    __syncthreads();
    int e0 = b * chunk, e1 = min(e0 + chunk, E);
    for (int e = e0 + tid; e < e1; e += 256) atomicAdd(&h[dst[e] >> 7], 1);
    __syncthreads();
    for (int k = tid; k < NB; k += 256) hist[(size_t)k * NBLK + b] = h[k];
}

// 3-kernel exclusive scan over M ints (M <= 256*1024)
__global__ __launch_bounds__(256) void k_part(const int* __restrict__ a,
                                              int* __restrict__ part, int M) {
    __shared__ int sums[256];
    int tid = threadIdx.x;
    int base = blockIdx.x * 1024 + tid * 4;
    int s = 0;
#pragma unroll
    for (int k = 0; k < 4; ++k) { int i = base + k; if (i < M) s += a[i]; }
    sums[tid] = s;
    __syncthreads();
    for (int off = 128; off > 0; off >>= 1) {
        if (tid < off) sums[tid] += sums[tid + off];
        __syncthreads();
    }
    if (tid == 0) part[blockIdx.x] = sums[0];
}

__global__ __launch_bounds__(256) void k_mid(int* __restrict__ part,
                                             int* __restrict__ ptrN,
                                             int nblk, int E) {
    __shared__ int s[256];
    int tid = threadIdx.x;
    s[tid] = (tid < nblk) ? part[tid] : 0;
    __syncthreads();
    for (int off = 1; off < 256; off <<= 1) {
        int v = (tid >= off) ? s[tid - off] : 0;
        __syncthreads();
        s[tid] += v;
        __syncthreads();
    }
    if (tid < nblk) part[tid] = tid ? s[tid - 1] : 0;
    if (tid == 0) ptrN[0] = E;
}

__global__ __launch_bounds__(256) void k_applyg(const int* __restrict__ a,
                                                const int* __restrict__ part,
                                                int* __restrict__ out, int M) {
    __shared__ int sums[256];
    int tid = threadIdx.x;
    int base = blockIdx.x * 1024 + tid * 4;
    int c[4];
    int s = 0;
#pragma unroll
    for (int k = 0; k < 4; ++k) {
        int i = base + k;
        c[k] = (i < M) ? a[i] : 0;
        s += c[k];
    }
    sums[tid] = s;
    __syncthreads();
    for (int off = 1; off < 256; off <<= 1) {
        int v = (tid >= off) ? sums[tid - off] : 0;
        __syncthreads();
        sums[tid] += v;
        __syncthreads();
    }
    int run = part[blockIdx.x] + (tid ? sums[tid - 1] : 0);
#pragma unroll
    for (int k = 0; k < 4; ++k) {
        int i = base + k;
        if (i < M) { out[i] = run; run += c[k]; }
    }
}

__global__ __launch_bounds__(256) void k_scat(const int* __restrict__ ei,
                                              const int* __restrict__ base,
                                              unsigned* __restrict__ packed,
                                              int E, int NB, int NBLK, int chunk) {
    __shared__ int fill[MAXNB];
    int tid = threadIdx.x, b = blockIdx.x;
    for (int k = tid; k < NB; k += 256) fill[k] = base[(size_t)k * NBLK + b];
    __syncthreads();
    int e0 = b * chunk, e1 = min(e0 + chunk, E);
    for (int e = e0 + tid; e < e1; e += 256) {
        int s = ei[e];
        int d = ei[E + e];
        int pos = atomicAdd(&fill[d >> 7], 1);
        packed[pos] = (unsigned)s | ((unsigned)(d & (NPB - 1)) << SRCB);
    }
}

// one block per bucket: counting-sort its segment by local dst.
// All global writes land in this block's own ~8KB segment (L2-combined).
__global__ __launch_bounds__(256) void k_sort(const unsigned* __restrict__ packed,
                                              const int* __restrict__ base,
                                              int* __restrict__ csr_src,
                                              int* __restrict__ ptr,
                                              float* __restrict__ dis,
                                              int E, int NB, int NBLK, int N) {
    __shared__ int cnt[NPB], scn[NPB], fill[NPB];
    int tid = threadIdx.x, k = blockIdx.x;
    int s0 = base[(size_t)k * NBLK];
    int s1 = (k + 1 < NB) ? base[(size_t)(k + 1) * NBLK] : E;
    if (tid < NPB) cnt[tid] = 0;
    __syncthreads();
    for (int j = s0 + tid; j < s1; j += 256) atomicAdd(&cnt[packed[j] >> SRCB], 1);
    __syncthreads();
    if (tid < NPB) scn[tid] = cnt[tid];
    __syncthreads();
    for (int off = 1; off < NPB; off <<= 1) {
        int v = (tid < NPB && tid >= off) ? scn[tid - off] : 0;
        __syncthreads();
        if (tid < NPB) scn[tid] += v;
        __syncthreads();
    }
    if (tid < NPB) {
        int excl = scn[tid] - cnt[tid];
        fill[tid] = excl;
        int gn = k * NPB + tid;
        if (gn < N) {
            ptr[gn] = s0 + excl;
            dis[gn] = rsqrtf((float)(cnt[tid] + 1));  // +1 self loop
        }
    }
    __syncthreads();
    for (int j = s0 + tid; j < s1; j += 256) {
        unsigned p = packed[j];
        int loc = atomicAdd(&fill[p >> SRCB], 1);
        csr_src[s0 + loc] = (int)(p & SRCMASK);
    }
}

// one wave per node; quarter-wave q (16 lanes x 16B = 256B bf16 row) handles
// edges j = lo+q, lo+q+4, ...  Unroll-4 main (16 rows in flight per wave),
// unroll-2 mid, single tail. Rows pre-scaled by dis[src]; self-loop weight-1;
// final scale by dd = dis[node].
#define ACC8(v)                         \
    do {                                \
        acc[0] += bflo((v).x);          \
        acc[1] += bfhi((v).x);          \
        acc[2] += bflo((v).y);          \
        acc[3] += bfhi((v).y);          \
        acc[4] += bflo((v).z);          \
        acc[5] += bfhi((v).z);          \
        acc[6] += bflo((v).w);          \
        acc[7] += bfhi((v).w);          \
    } while (0)

__global__ __launch_bounds__(256) void k_gather(char* __restrict__ outc,
                                                const int* __restrict__ csr_src,
                                                const int* __restrict__ ptr,
                                                const float* __restrict__ dis,
                                                int N) {
    int lane = threadIdx.x & 63;
    int q = lane >> 4, sub = lane & 15;
    int node = (blockIdx.x * blockDim.x + threadIdx.x) >> 6;
    if (node >= N) return;
    int lo = ptr[node], hi = ptr[node + 1];
    float dd = dis[node];
    const char* xb = outc + 256 + (size_t)sub * 16;  // pre-scaled bf16 row halves

    float acc[8] = {0.f, 0.f, 0.f, 0.f, 0.f, 0.f, 0.f, 0.f};

    if (q == 0) {  // self-loop: pre-scaled row, weight 1
        uint4 v = *(const uint4*)(xb + (size_t)node * 512);
        ACC8(v);
    }
    int j = lo + q;
    for (; j + 12 < hi; j += 16) {  // 4 edges per quarter-wave in flight
        int s0 = csr_src[j];
        int s1 = csr_src[j + 4];
        int s2 = csr_src[j + 8];
        int s3 = csr_src[j + 12];
        uint4 v0 = *(const uint4*)(xb + (size_t)s0 * 512);
        uint4 v1 = *(const uint4*)(xb + (size_t)s1 * 512);
        uint4 v2 = *(const uint4*)(xb + (size_t)s2 * 512);
        uint4 v3 = *(const uint4*)(xb + (size_t)s3 * 512);
        ACC8(v0);
        ACC8(v1);
        ACC8(v2);
        ACC8(v3);
    }
    for (; j + 4 < hi; j += 8) {    // mid: 2 in flight
        int s0 = csr_src[j];
        int s1 = csr_src[j + 4];
        uint4 v0 = *(const uint4*)(xb + (size_t)s0 * 512);
        uint4 v1 = *(const uint4*)(xb + (size_t)s1 * 512);
        ACC8(v0);
        ACC8(v1);
    }
    if (j < hi) {
        int s = csr_src[j];
        uint4 v = *(const uint4*)(xb + (size_t)s * 512);
        ACC8(v);
    }
#pragma unroll
    for (int i = 0; i < 8; ++i) {
        acc[i] += __shfl_xor(acc[i], 16);
        acc[i] += __shfl_xor(acc[i], 32);
    }
    if (q == 0) {
        uint4 o;
        o.x = pack2(dd * acc[0], dd * acc[1]);
        o.y = pack2(dd * acc[2], dd * acc[3]);
        o.z = pack2(dd * acc[4], dd * acc[5]);
        o.w = pack2(dd * acc[6], dd * acc[7]);
        *(uint4*)(outc + (size_t)node * 512 + sub * 16) = o;
    }
}

// MFMA GEMM: block = 256 thr (4 waves), 128 rows/block (wave: 2 row-tiles of 16).
// A = agg_bf16 (out rows' first halves), B = W^T bf16 in LDS.
// C/D layout: col=lane&15, row=(lane>>4)*4+reg.
__global__ __launch_bounds__(256) void k_gemm(const float* __restrict__ x,
                                              const float* __restrict__ W,
                                              const float* __restrict__ bias,
                                              float* __restrict__ out, int N) {
    __shared__ short Wt[128 * 136];
    int tid = threadIdx.x;
    for (int i = tid; i < 8192; i += 256) {
        int n = i & 127, k2 = i >> 7;
        float w0 = W[(size_t)(2 * k2) * 128 + n];
        float w1 = W[(size_t)(2 * k2 + 1) * 128 + n];
        *(unsigned*)(Wt + (size_t)n * 136 + 2 * k2) = pack2(w0, w1);
    }
    __syncthreads();

    int lane = tid & 63, wv = tid >> 6;
    int quad = lane >> 4, l16 = lane & 15;
    size_t rowb = (size_t)blockIdx.x * 128 + wv * 32;
    const char* aggc = (const char*)out;

    floatx4 acc[2][8];
#pragma unroll
    for (int rt = 0; rt < 2; ++rt)
#pragma unroll
        for (int c = 0; c < 8; ++c) acc[rt][c] = (floatx4)0.0f;

    size_t r0 = rowb + l16;      if (r0 >= (size_t)N) r0 = N - 1;
    size_t r1 = rowb + 16 + l16; if (r1 >= (size_t)N) r1 = N - 1;

    for (int ks = 0; ks < 4; ++ks) {
        int koff = (quad * 8 + ks * 32) * 2;
        short8 a0 = *(const short8*)(aggc + r0 * 512 + koff);
        short8 a1 = *(const short8*)(aggc + r1 * 512 + koff);
#pragma unroll
        for (int c = 0; c < 8; ++c) {
            short8 bf = *(const short8*)(Wt + (size_t)(c * 16 + l16) * 136 + quad * 8 + ks * 32);
            acc[0][c] = __builtin_amdgcn_mfma_f32_16x16x32_bf16(a0, bf, acc[0][c], 0, 0, 0);
            acc[1][c] = __builtin_amdgcn_mfma_f32_16x16x32_bf16(a1, bf, acc[1][c], 0, 0, 0);
        }
    }

#pragma unroll
    for (int rt = 0; rt < 2; ++rt) {
#pragma unroll
        for (int c = 0; c < 8; ++c) {
            float bb = bias[c * 16 + l16];
#pragma unroll
            for (int r = 0; r < 4; ++r) {
                size_t row = rowb + rt * 16 + quad * 4 + r;
                if (row < (size_t)N) {
                    size_t idx = row * 128 + c * 16 + l16;
                    out[idx] = x[idx] + acc[rt][c][r] + bb;
                }
            }
        }
    }
}

extern "C" void kernel_launch(void* const* d_in, const int* in_sizes, int n_in,
                              void* d_out, int out_size, void* d_ws, size_t ws_size,
                              hipStream_t stream) {
    const float* x  = (const float*)d_in[0];
    const int*   ei = (const int*)d_in[1];   // [2, E]: src row then dst row
    const float* W  = (const float*)d_in[2];
    const float* b  = (const float*)d_in[3];
    float* out = (float*)d_out;

    int N = in_sizes[0] / 128;
    int E = in_sizes[1] / 2;
    int NB = (N + NPB - 1) / NPB;            // 782 buckets

    // Pick chunk for CSR-build parallelism: 6144 -> ~261 blocks (vs 98 at
    // 16384). Fall back to 16384 if workspace can't hold the bigger hist.
    int chunk = 6144;
    int NBLK, M, nscan;
    size_t need;
    for (;;) {
        NBLK = (E + chunk - 1) / chunk;
        M    = NB * NBLK;
        nscan = (M + 1023) / 1024;
        need = (size_t)4 * ((size_t)2 * E + N + (N + 1) + (size_t)2 * M + 256);
        if (need <= ws_size || chunk >= 16384) break;
        chunk = 16384;
    }
    // nscan must fit k_mid's 256-wide scan
    // (E=1.6M, chunk=6144 -> NBLK=261, M=204102, nscan=200)

    // ws: packed[E] | csr_src[E] | dis[N] | ptr[N+1] | hist[M] | base[M] | part[256]
    char* w = (char*)d_ws;
    unsigned* packed = (unsigned*)w; w += (size_t)E * 4;
    int*   csr_src = (int*)w;   w += (size_t)E * 4;
    float* dis     = (float*)w; w += (size_t)N * 4;
    int*   ptr     = (int*)w;   w += (size_t)(N + 1) * 4;
    int*   hist    = (int*)w;   w += (size_t)M * 4;
    int*   base    = (int*)w;   w += (size_t)M * 4;
    int*   part    = (int*)w;

    k_hist<<<NBLK, 256, 0, stream>>>(ei + E, hist, E, NB, NBLK, chunk);
    k_part<<<nscan, 256, 0, stream>>>(hist, part, M);
    k_mid<<<1, 256, 0, stream>>>(part, ptr + N, nscan, E);
    k_applyg<<<nscan, 256, 0, stream>>>(hist, part, base, M);
    k_scat<<<NBLK, 256, 0, stream>>>(ei, base, packed, E, NB, NBLK, chunk);
    k_sort<<<NB, 256, 0, stream>>>(packed, base, csr_src, ptr, dis, E, NB, NBLK, N);
    k_cvt<<<(N * 16 + 255) / 256, 256, 0, stream>>>(x, dis, (char*)out, N);
    k_gather<<<((size_t)N * 64 + 255) / 256, 256, 0, stream>>>((char*)out, csr_src, ptr, dis, N);
    k_gemm<<<(N + 127) / 128, 256, 0, stream>>>(x, W, b, out, N);
}